// Round 10
// baseline (847.942 us; speedup 1.0000x reference)
//
// R10: R3 structure + per-call fp32 TRANSPOSE of W_lv1/W_lv2 into d_ws.
// Thread owning output dim i now reads Wt[i][j..j+3] as float4 (contiguous):
// 4x fewer load issues, ~75% L1-hit from 64B-line reuse. Weights stay exact
// fp32 (R9 proved any quantization explodes: absmax 0.836).
#include <hip/hip_runtime.h>

#define kT 8
#define kG 120
#define kP 400
#define kObj 45
#define kS 10
#define kHid 200

__device__ __constant__ int c_gmap[40] = {
    0,1,2,3,4,5,6,7,8,9,
    30,31,32,33,34,35,36,37,38,39,
    60,61,62,63,64,65,66,67,
    84,85,86,87,88,89,
    102,103,104,105,106,107};

__device__ __constant__ float c_freq[5] = {0.01f, 0.7f, 0.91f, 0.97f, 0.99f};

__device__ __forceinline__ float leaky_clamp(float x) {
    x = fminf(fmaxf(x, -1.0f), 1.0f);
    return x > 0.0f ? x : 0.01f * x;
}

// LDS-tiled 400x400 transpose, coalesced on both sides. 400 = 25*16 exact.
// grid (25,25,2), block (16,16). z selects matrix.
__global__ __launch_bounds__(256) void transpose_kernel(
    const float* __restrict__ W_lv1, const float* __restrict__ W_lv2,
    float* __restrict__ ws)
{
    __shared__ float tile[16][17];
    const float* src = (blockIdx.z == 0) ? W_lv1 : W_lv2;
    float* dst = ws + blockIdx.z * (kP * kP);
    int ti = blockIdx.x * 16;   // output-row block (i)
    int tj = blockIdx.y * 16;   // output-col block (j)
    int tx = threadIdx.x, ty = threadIdx.y;
    // read src[j][i]: row j = tj+ty, col i = ti+tx (tx contiguous -> coalesced)
    tile[ty][tx] = src[(tj + ty) * kP + (ti + tx)];
    __syncthreads();
    // write dst[i][j]: row i = ti+ty, col j = tj+tx (tx contiguous -> coalesced)
    dst[(ti + ty) * kP + (tj + tx)] = tile[tx][ty];
}

__global__ __launch_bounds__(256) void tem_kernel(
    const float* __restrict__ g_seq, const int* __restrict__ x_idx,
    const float* __restrict__ W_comp, const float* __restrict__ W_repeat,
    const float* __restrict__ W_tile, const float* __restrict__ W_tile0,
    const float* __restrict__ w_x, const float* __restrict__ b_x,
    const float* __restrict__ W1, const float* __restrict__ b1,
    const float* __restrict__ W2, const float* __restrict__ b2,
    const float* __restrict__ Wt1, const float* __restrict__ Wt2,
    const float* __restrict__ b_lv1, const float* __restrict__ b_lv2,
    float* __restrict__ out)
{
    const int b   = blockIdx.x;
    const int tid = threadIdx.x;
    const int i1  = tid;
    const int i2  = tid + 256;
    const bool has2 = (tid < kP - 256);   // tid < 144

    __shared__ __align__(16) float s_xflat[50];
    __shared__ float s_xc[kS];
    __shared__ float s_gdown[40];
    __shared__ __align__(16) float s_pinf[kP];
    __shared__ __align__(16) float s_h[kP];
    __shared__ float s_pt[kP];
    __shared__ float s_u[kT][kP];
    __shared__ float s_v[kT][kP];
    __shared__ float s_red[4][kT];
    __shared__ float s_dots[kT];
    __shared__ float s_coef[kT];
    __shared__ float s_xs[kS];
    __shared__ float s_hid[kHid];

    if (tid < 50) s_xflat[tid] = 0.0f;
    __syncthreads();

    for (int t = 0; t < kT; ++t) {
        if (tid < kS) {
            int idx = x_idx[b * kT + t];
            s_xc[tid] = W_comp[idx * kS + tid];
        }
        if (tid < 40) {
            s_gdown[tid] = g_seq[(b * kT + t) * kG + c_gmap[tid]];
        }
        if (tid == 0) {
            float c = 0.5f;
            for (int s = t - 1; s >= 0; --s) { s_coef[s] = c; c *= 0.9999f; }
        }
        __syncthreads();

        if (tid < 50) {
            float f = c_freq[tid / 10];
            s_xflat[tid] = (1.0f - f) * s_xflat[tid] + f * s_xc[tid % 10];
        }
        __syncthreads();

        {
            float ge1 = 0.0f, ge2 = 0.0f;
            #pragma unroll
            for (int j = 0; j < 40; ++j) {
                float g = s_gdown[j];
                ge1 += g * W_repeat[i1 * 40 + j];
                if (has2) ge2 += g * W_repeat[i2 * 40 + j];
            }
            float xe1 = 0.0f, xe2 = 0.0f;
            #pragma unroll
            for (int j = 0; j < 50; ++j) {
                float x = s_xflat[j];
                xe1 += x * W_tile[i1 * 50 + j];
                if (has2) xe2 += x * W_tile[i2 * 50 + j];
            }
            s_pinf[i1] = leaky_clamp(ge1 * xe1);
            s_h[i1]    = leaky_clamp(ge1);
            if (has2) {
                s_pinf[i2] = leaky_clamp(ge2 * xe2);
                s_h[i2]    = leaky_clamp(ge2);
            }
        }
        __syncthreads();

        if (t == 0) {
            float h1 = s_h[i1];
            float h2 = has2 ? s_h[i2] : 0.0f;
            #pragma unroll
            for (int it = 0; it < 5; ++it) {
                h1 = leaky_clamp(0.8f * h1);
                if (has2) h2 = leaky_clamp(0.8f * h2);
            }
            s_h[i1] = h1;
            if (has2) s_h[i2] = h2;
            __syncthreads();
        } else {
            for (int it = 0; it < 5; ++it) {
                float h1 = s_h[i1];
                float h2 = has2 ? s_h[i2] : 0.0f;
                for (int s = 0; s < t; ++s) {
                    float p = s_v[s][i1] * h1;
                    if (has2) p += s_v[s][i2] * h2;
                    #pragma unroll
                    for (int off = 32; off; off >>= 1) p += __shfl_down(p, off, 64);
                    if ((tid & 63) == 0) s_red[tid >> 6][s] = p;
                }
                __syncthreads();
                if (tid < t)
                    s_dots[tid] = s_red[0][tid] + s_red[1][tid] + s_red[2][tid] + s_red[3][tid];
                __syncthreads();
                float mh1 = 0.0f, mh2 = 0.0f;
                for (int s = 0; s < t; ++s) {
                    float cd = s_coef[s] * s_dots[s];
                    mh1 += cd * s_u[s][i1];
                    if (has2) mh2 += cd * s_u[s][i2];
                }
                s_h[i1] = leaky_clamp(0.8f * h1 + mh1);
                if (has2) s_h[i2] = leaky_clamp(0.8f * h2 + mh2);
                __syncthreads();
            }
        }

        // ---- precision matvecs on TRANSPOSED weights, float4 row-walk ----
        {
            const float4* w1a = (const float4*)(Wt1 + i1 * kP);
            const float4* w2a = (const float4*)(Wt2 + i1 * kP);
            const float4* w1b = (const float4*)(Wt1 + i2 * kP);
            const float4* w2b = (const float4*)(Wt2 + i2 * kP);
            const float4* sp  = (const float4*)s_pinf;
            const float4* sh  = (const float4*)s_h;
            float a1x=0.f,a1y=0.f,a1z=0.f,a1w=0.f;   // lv1 dim i1
            float c1x=0.f,c1y=0.f,c1z=0.f,c1w=0.f;   // lv2 dim i1
            float a2x=0.f,a2y=0.f,a2z=0.f,a2w=0.f;   // lv1 dim i2
            float c2x=0.f,c2y=0.f,c2z=0.f,c2w=0.f;   // lv2 dim i2
            #pragma unroll 2
            for (int jv = 0; jv < kP / 4; ++jv) {
                float4 p = sp[jv];
                float4 r = sh[jv];
                float4 wa = w1a[jv];
                float4 wc = w2a[jv];
                a1x += p.x * wa.x; a1y += p.y * wa.y;
                a1z += p.z * wa.z; a1w += p.w * wa.w;
                c1x += r.x * wc.x; c1y += r.y * wc.y;
                c1z += r.z * wc.z; c1w += r.w * wc.w;
                if (has2) {
                    float4 wb = w1b[jv];
                    float4 wd = w2b[jv];
                    a2x += p.x * wb.x; a2y += p.y * wb.y;
                    a2z += p.z * wb.z; a2w += p.w * wb.w;
                    c2x += r.x * wd.x; c2y += r.y * wd.y;
                    c2z += r.z * wd.z; c2w += r.w * wd.w;
                }
            }
            {
                float lv1 = -2.0f + 6.0f * tanhf((a1x + a1y + a1z + a1w + b_lv1[i1]) * (1.0f / 6.0f));
                float lv2 = -2.0f + 6.0f * tanhf((c1x + c1y + c1z + c1w + b_lv2[i1]) * (1.0f / 6.0f));
                float inv1 = expf(-lv1), inv2 = expf(-lv2);
                float pr = s_h[i1];
                float p  = (s_pinf[i1] * inv1 + pr * inv2) / (inv1 + inv2);
                s_pt[i1] = p;
                s_u[t][i1] = p - pr;
                s_v[t][i1] = p + pr;
            }
            if (has2) {
                float lv1 = -2.0f + 6.0f * tanhf((a2x + a2y + a2z + a2w + b_lv1[i2]) * (1.0f / 6.0f));
                float lv2 = -2.0f + 6.0f * tanhf((c2x + c2y + c2z + c2w + b_lv2[i2]) * (1.0f / 6.0f));
                float inv1 = expf(-lv1), inv2 = expf(-lv2);
                float pr = s_h[i2];
                float p  = (s_pinf[i2] * inv1 + pr * inv2) / (inv1 + inv2);
                s_pt[i2] = p;
                s_u[t][i2] = p - pr;
                s_v[t][i2] = p + pr;
            }
        }
        __syncthreads();

        if (tid < kS) {
            float acc = 0.0f;
            for (int j = 0; j < 100; ++j)
                acc += s_pt[j] * W_tile0[j * kS + tid];
            s_xs[tid] = w_x[0] * acc + b_x[tid];
        }
        __syncthreads();
        if (tid < kHid) {
            float acc = b1[tid];
            #pragma unroll
            for (int d = 0; d < kS; ++d)
                acc += s_xs[d] * W1[d * kHid + tid];
            s_hid[tid] = acc > 0.0f ? acc : (expf(acc) - 1.0f);
        }
        __syncthreads();
        if (tid < kObj) {
            float acc = b2[tid];
            for (int h = 0; h < kHid; ++h)
                acc += s_hid[h] * W2[h * kObj + tid];
            out[(b * kT + t) * kObj + tid] = acc;
        }
        __syncthreads();
    }
}

extern "C" void kernel_launch(void* const* d_in, const int* in_sizes, int n_in,
                              void* d_out, int out_size, void* d_ws, size_t ws_size,
                              hipStream_t stream) {
    const float* g_seq   = (const float*)d_in[0];
    const int*   x_idx   = (const int*)d_in[1];
    const float* W_comp  = (const float*)d_in[2];
    const float* W_repeat= (const float*)d_in[3];
    const float* W_tile  = (const float*)d_in[4];
    const float* W_tile0 = (const float*)d_in[5];
    const float* w_x     = (const float*)d_in[6];
    const float* b_x     = (const float*)d_in[7];
    const float* W1      = (const float*)d_in[8];
    const float* b1      = (const float*)d_in[9];
    const float* W2      = (const float*)d_in[10];
    const float* b2      = (const float*)d_in[11];
    const float* W_lv1   = (const float*)d_in[12];
    const float* b_lv1   = (const float*)d_in[13];
    const float* W_lv2   = (const float*)d_in[14];
    const float* b_lv2   = (const float*)d_in[15];
    float* out = (float*)d_out;

    float* Wt1 = (float*)d_ws;              // [kP][kP] transposed W_lv1
    float* Wt2 = Wt1 + kP * kP;             // [kP][kP] transposed W_lv2

    transpose_kernel<<<dim3(25, 25, 2), dim3(16, 16), 0, stream>>>(W_lv1, W_lv2, Wt1);

    const int Bn = in_sizes[0] / (kT * kG);
    tem_kernel<<<dim3(Bn), dim3(256), 0, stream>>>(
        g_seq, x_idx, W_comp, W_repeat, W_tile, W_tile0, w_x, b_x,
        W1, b1, W2, b2, Wt1, Wt2, b_lv1, b_lv2, out);
}

// Round 11
// 323.989 us; speedup vs baseline: 2.6172x; 2.6172x over previous
//
// R11: R8 base + matvec restructured: float4 along i on ORIGINAL W layout
// (coalesced AND vectorized), 4 groups x 128 thr split {matrix} x {j-half};
// 200 float4 loads/thread/step in 8 chains = 25 serial rounds (R8: 100).
// Partials combined via LDS. Weights exact fp32 (R9: quantization explodes).
#include <hip/hip_runtime.h>

#define kT 8
#define kG 120
#define kP 400
#define kObj 45
#define kS 10
#define kHid 200

__device__ __constant__ int c_gmap[40] = {
    0,1,2,3,4,5,6,7,8,9,
    30,31,32,33,34,35,36,37,38,39,
    60,61,62,63,64,65,66,67,
    84,85,86,87,88,89,
    102,103,104,105,106,107};

__device__ __constant__ float c_freq[5] = {0.01f, 0.7f, 0.91f, 0.97f, 0.99f};

__device__ __forceinline__ float leaky_clamp(float x) {
    x = fminf(fmaxf(x, -1.0f), 1.0f);
    return x > 0.0f ? x : 0.01f * x;
}

__global__ __launch_bounds__(512) void tem_kernel(
    const float* __restrict__ g_seq, const int* __restrict__ x_idx,
    const float* __restrict__ W_comp, const float* __restrict__ W_repeat,
    const float* __restrict__ W_tile, const float* __restrict__ W_tile0,
    const float* __restrict__ w_x, const float* __restrict__ b_x,
    const float* __restrict__ W1, const float* __restrict__ b1,
    const float* __restrict__ W2, const float* __restrict__ b2,
    const float* __restrict__ W_lv1, const float* __restrict__ b_lv1,
    const float* __restrict__ W_lv2, const float* __restrict__ b_lv2,
    float* __restrict__ out)
{
    const int b   = blockIdx.x;
    const int tid = threadIdx.x;
    const int dim = tid;
    const bool hasD = (tid < kP);
    const int wid  = tid >> 6;
    const int lane = tid & 63;
    // matvec grouping: 4 groups x 128 threads; within group r<100 active.
    const int g   = tid >> 7;            // 0..3
    const int r   = tid & 127;           // 0..127
    const bool mact = (r < 100);
    const int j0  = (g & 1) * 200;       // j-half

    __shared__ float s_xflat[50];
    __shared__ float s_xc[kS];
    __shared__ float s_gdown[40];
    __shared__ __align__(16) float s_pinf[kP];
    __shared__ __align__(16) float s_h[kP];
    __shared__ float s_pt[kP];
    __shared__ float s_u[kT][kP];
    __shared__ float s_v[kT][kP];
    __shared__ __align__(16) float s_part[4][kP];   // matvec partials
    __shared__ float s_red[kT][8];
    __shared__ float s_dots[kT];
    __shared__ float s_coef[kT];
    __shared__ float s_xs[kS];
    __shared__ float s_hid[kHid];

    const float blv1 = hasD ? b_lv1[dim] : 0.0f;
    const float blv2 = hasD ? b_lv2[dim] : 0.0f;

    if (tid < 50) s_xflat[tid] = 0.0f;
    __syncthreads();

    for (int t = 0; t < kT; ++t) {
        // ---- staging ----
        if (tid < kS) {
            int idx = x_idx[b * kT + t];
            s_xc[tid] = W_comp[idx * kS + tid];
        } else if (tid >= 64 && tid < 104) {
            s_gdown[tid - 64] = g_seq[(b * kT + t) * kG + c_gmap[tid - 64]];
        } else if (tid == 128) {
            float c = 0.5f;
            for (int s = t - 1; s >= 0; --s) { s_coef[s] = c; c *= 0.9999f; }
        }
        __syncthreads();

        // ---- temporal filter ----
        if (tid < 50) {
            float f = c_freq[tid / 10];
            s_xflat[tid] = (1.0f - f) * s_xflat[tid] + f * s_xc[tid % 10];
        }
        __syncthreads();

        // ---- g_exp, x_exp, p_inf, h init ----
        if (hasD) {
            float ge = 0.0f;
            #pragma unroll
            for (int j = 0; j < 40; ++j)
                ge += s_gdown[j] * W_repeat[dim * 40 + j];
            float xe = 0.0f;
            #pragma unroll
            for (int j = 0; j < 50; ++j)
                xe += s_xflat[j] * W_tile[dim * 50 + j];
            s_pinf[dim] = leaky_clamp(ge * xe);
            s_h[dim]    = leaky_clamp(ge);
        }
        __syncthreads();

        // ---- attractor (rank-<=t factorized M) ----
        if (t == 0) {
            if (hasD) {
                float h = s_h[dim];
                #pragma unroll
                for (int it = 0; it < 5; ++it) h = leaky_clamp(0.8f * h);
                s_h[dim] = h;
            }
            __syncthreads();
        } else {
            for (int it = 0; it < 5; ++it) {
                float h = hasD ? s_h[dim] : 0.0f;
                for (int s = 0; s < t; ++s) {
                    float p = hasD ? s_v[s][dim] * h : 0.0f;
                    #pragma unroll
                    for (int off = 32; off; off >>= 1) p += __shfl_down(p, off, 64);
                    if (lane == 0 && wid < 7) s_red[s][wid] = p;
                }
                __syncthreads();
                if (tid < t) {
                    float d = 0.0f;
                    #pragma unroll
                    for (int w = 0; w < 7; ++w) d += s_red[tid][w];
                    s_dots[tid] = d;
                }
                __syncthreads();
                if (hasD) {
                    float mh = 0.0f;
                    for (int s = 0; s < t; ++s)
                        mh += s_coef[s] * s_dots[s] * s_u[s][dim];
                    s_h[dim] = leaky_clamp(0.8f * h + mh);
                }
                __syncthreads();
            }
        }

        // ---- precision matvecs: float4 along i, group-split over matrix x j-half ----
        {
            auto mv = [&](const float* __restrict__ W, const float* vec) {
                float4 a0{0,0,0,0}, a1{0,0,0,0}, a2{0,0,0,0}, a3{0,0,0,0};
                float4 a4{0,0,0,0}, a5{0,0,0,0}, a6{0,0,0,0}, a7{0,0,0,0};
                #pragma unroll 1
                for (int jj = 0; jj < 200; jj += 8) {
                    int j = j0 + jj;
                    float4 w0 = ((const float4*)(W + (j+0) * kP))[r];
                    float4 w1v = ((const float4*)(W + (j+1) * kP))[r];
                    float4 w2v = ((const float4*)(W + (j+2) * kP))[r];
                    float4 w3 = ((const float4*)(W + (j+3) * kP))[r];
                    float4 w4 = ((const float4*)(W + (j+4) * kP))[r];
                    float4 w5 = ((const float4*)(W + (j+5) * kP))[r];
                    float4 w6 = ((const float4*)(W + (j+6) * kP))[r];
                    float4 w7 = ((const float4*)(W + (j+7) * kP))[r];
                    float v0 = vec[j+0], v1 = vec[j+1], v2 = vec[j+2], v3 = vec[j+3];
                    float v4 = vec[j+4], v5 = vec[j+5], v6 = vec[j+6], v7 = vec[j+7];
                    a0.x += w0.x * v0; a0.y += w0.y * v0; a0.z += w0.z * v0; a0.w += w0.w * v0;
                    a1.x += w1v.x * v1; a1.y += w1v.y * v1; a1.z += w1v.z * v1; a1.w += w1v.w * v1;
                    a2.x += w2v.x * v2; a2.y += w2v.y * v2; a2.z += w2v.z * v2; a2.w += w2v.w * v2;
                    a3.x += w3.x * v3; a3.y += w3.y * v3; a3.z += w3.z * v3; a3.w += w3.w * v3;
                    a4.x += w4.x * v4; a4.y += w4.y * v4; a4.z += w4.z * v4; a4.w += w4.w * v4;
                    a5.x += w5.x * v5; a5.y += w5.y * v5; a5.z += w5.z * v5; a5.w += w5.w * v5;
                    a6.x += w6.x * v6; a6.y += w6.y * v6; a6.z += w6.z * v6; a6.w += w6.w * v6;
                    a7.x += w7.x * v7; a7.y += w7.y * v7; a7.z += w7.z * v7; a7.w += w7.w * v7;
                }
                float4 s01, s23, s45, s67, sA, sB, tot;
                s01.x=a0.x+a1.x; s01.y=a0.y+a1.y; s01.z=a0.z+a1.z; s01.w=a0.w+a1.w;
                s23.x=a2.x+a3.x; s23.y=a2.y+a3.y; s23.z=a2.z+a3.z; s23.w=a2.w+a3.w;
                s45.x=a4.x+a5.x; s45.y=a4.y+a5.y; s45.z=a4.z+a5.z; s45.w=a4.w+a5.w;
                s67.x=a6.x+a7.x; s67.y=a6.y+a7.y; s67.z=a6.z+a7.z; s67.w=a6.w+a7.w;
                sA.x=s01.x+s23.x; sA.y=s01.y+s23.y; sA.z=s01.z+s23.z; sA.w=s01.w+s23.w;
                sB.x=s45.x+s67.x; sB.y=s45.y+s67.y; sB.z=s45.z+s67.z; sB.w=s45.w+s67.w;
                tot.x=sA.x+sB.x; tot.y=sA.y+sB.y; tot.z=sA.z+sB.z; tot.w=sA.w+sB.w;
                ((float4*)&s_part[g][0])[r] = tot;
            };
            if (mact) {
                if (g < 2) mv(W_lv1, s_pinf);
                else       mv(W_lv2, s_h);
            }
        }
        __syncthreads();

        // ---- fusion (thread owns dim tid) ----
        if (hasD) {
            float lv1raw = s_part[0][dim] + s_part[1][dim] + blv1;
            float lv2raw = s_part[2][dim] + s_part[3][dim] + blv2;
            float lv1 = -2.0f + 6.0f * tanhf(lv1raw * (1.0f / 6.0f));
            float lv2 = -2.0f + 6.0f * tanhf(lv2raw * (1.0f / 6.0f));
            float inv1 = expf(-lv1), inv2 = expf(-lv2);
            float pr = s_h[dim];
            float p  = (s_pinf[dim] * inv1 + pr * inv2) / (inv1 + inv2);
            s_pt[dim] = p;
            s_u[t][dim] = p - pr;
            s_v[t][dim] = p + pr;
        }
        __syncthreads();

        // ---- generative decode ----
        if (tid < kS) {
            float acc = 0.0f;
            for (int j = 0; j < 100; ++j)
                acc += s_pt[j] * W_tile0[j * kS + tid];
            s_xs[tid] = w_x[0] * acc + b_x[tid];
        }
        __syncthreads();
        if (tid < kHid) {
            float acc = b1[tid];
            #pragma unroll
            for (int d = 0; d < kS; ++d)
                acc += s_xs[d] * W1[d * kHid + tid];
            s_hid[tid] = acc > 0.0f ? acc : (expf(acc) - 1.0f);
        }
        __syncthreads();
        if (tid < kObj) {
            float acc = b2[tid];
            for (int h = 0; h < kHid; ++h)
                acc += s_hid[h] * W2[h * kObj + tid];
            out[(b * kT + t) * kObj + tid] = acc;
        }
        __syncthreads();
    }
}

extern "C" void kernel_launch(void* const* d_in, const int* in_sizes, int n_in,
                              void* d_out, int out_size, void* d_ws, size_t ws_size,
                              hipStream_t stream) {
    const float* g_seq   = (const float*)d_in[0];
    const int*   x_idx   = (const int*)d_in[1];
    const float* W_comp  = (const float*)d_in[2];
    const float* W_repeat= (const float*)d_in[3];
    const float* W_tile  = (const float*)d_in[4];
    const float* W_tile0 = (const float*)d_in[5];
    const float* w_x     = (const float*)d_in[6];
    const float* b_x     = (const float*)d_in[7];
    const float* W1      = (const float*)d_in[8];
    const float* b1      = (const float*)d_in[9];
    const float* W2      = (const float*)d_in[10];
    const float* b2      = (const float*)d_in[11];
    const float* W_lv1   = (const float*)d_in[12];
    const float* b_lv1   = (const float*)d_in[13];
    const float* W_lv2   = (const float*)d_in[14];
    const float* b_lv2   = (const float*)d_in[15];
    float* out = (float*)d_out;

    const int Bn = in_sizes[0] / (kT * kG);
    tem_kernel<<<dim3(Bn), dim3(512), 0, stream>>>(
        g_seq, x_idx, W_comp, W_repeat, W_tile, W_tile0, w_x, b_x,
        W1, b1, W2, b2, W_lv1, b_lv1, W_lv2, b_lv2, out);
}

// Round 12
// 255.541 us; speedup vs baseline: 3.3182x; 1.2679x over previous
//
// R12: single kernel, 256 blocks x 512 thr. Transaction model (fits R3/R8/R10/R11):
// time = lines streamed per block, ~1 line/cy/CU. Hoist the feed-forward parts
// out of the step loop: p_inf(t), h_init(t) and lv1raw(t)=W_lv1@p_inf(t) for all
// 8 t computed in a prologue (W_lv1 read ONCE per block, not 8x). Per-step keeps
// only the recurrent lv2=W_lv2@p_ret stream (10K lines). Weights exact fp32.
#include <hip/hip_runtime.h>

#define kT 8
#define kG 120
#define kP 400
#define kObj 45
#define kS 10
#define kHid 200

__device__ __constant__ int c_gmap[40] = {
    0,1,2,3,4,5,6,7,8,9,
    30,31,32,33,34,35,36,37,38,39,
    60,61,62,63,64,65,66,67,
    84,85,86,87,88,89,
    102,103,104,105,106,107};

__device__ __constant__ float c_freq[5] = {0.01f, 0.7f, 0.91f, 0.97f, 0.99f};

__device__ __forceinline__ float leaky_clamp(float x) {
    x = fminf(fmaxf(x, -1.0f), 1.0f);
    return x > 0.0f ? x : 0.01f * x;
}

__global__ __launch_bounds__(512) void tem_kernel(
    const float* __restrict__ g_seq, const int* __restrict__ x_idx,
    const float* __restrict__ W_comp, const float* __restrict__ W_repeat,
    const float* __restrict__ W_tile, const float* __restrict__ W_tile0,
    const float* __restrict__ w_x, const float* __restrict__ b_x,
    const float* __restrict__ W1, const float* __restrict__ b1,
    const float* __restrict__ W2, const float* __restrict__ b2,
    const float* __restrict__ W_lv1, const float* __restrict__ b_lv1,
    const float* __restrict__ W_lv2, const float* __restrict__ b_lv2,
    float* __restrict__ out)
{
    const int b   = blockIdx.x;
    const int tid = threadIdx.x;
    const int dim = tid;
    const bool hasD = (tid < kP);
    const int wid  = tid >> 6;
    const int lane = tid & 63;

    __shared__ __align__(16) float pT[kP][kT];    // p_inf, t-minor
    __shared__ __align__(16) float hT[kP][kT];    // h_init = lc(g_exp)
    __shared__ __align__(16) float lvT[kP][kT];   // lv1raw (pre-bias)
    __shared__ __align__(16) float xfT[50][kT];   // x_filt, t-minor
    __shared__ __align__(16) float gdT[40][kT];   // g_down, t-minor
    __shared__ float s_h[kP];                     // p_ret of current step
    __shared__ float s_pt[kP];
    __shared__ float s_u[kT][kP];
    __shared__ float s_v[kT][kP];
    __shared__ float s_red[2][kT][8];             // [parity][s][wave]
    __shared__ int   s_idx[kT];
    __shared__ float s_xsp[kS][kS];               // [chunk][d]
    __shared__ float s_xs[kS];
    __shared__ float s_hid[kHid];
    __shared__ float s_lp[8][kObj];

    const float blv1 = hasD ? b_lv1[dim] : 0.0f;
    const float blv2 = hasD ? b_lv2[dim] : 0.0f;
    const float wx   = w_x[0];

    // ================= prologue =================
    if (tid < kT) s_idx[tid] = x_idx[b * kT + tid];
    __syncthreads();

    if (tid < 40) {
        int gi = c_gmap[tid];
        #pragma unroll
        for (int t = 0; t < kT; ++t)
            gdT[tid][t] = g_seq[(b * kT + t) * kG + gi];
    } else if (tid >= 64 && tid < 114) {
        int r = tid - 64, d = r % 10;
        float f = c_freq[r / 10];
        float xf = 0.0f;
        #pragma unroll
        for (int t = 0; t < kT; ++t) {
            float xc = W_comp[s_idx[t] * kS + d];
            xf = (1.0f - f) * xf + f * xc;
            xfT[r][t] = xf;
        }
    }
    __syncthreads();

    // projections for all 8 t: g_exp, x_exp -> p_inf, h_init
    if (hasD) {
        float ge[kT], xe[kT];
        #pragma unroll
        for (int t = 0; t < kT; ++t) { ge[t] = 0.0f; xe[t] = 0.0f; }
        for (int j = 0; j < 40; ++j) {
            float w = W_repeat[dim * 40 + j];
            float4 gA = *(const float4*)&gdT[j][0];
            float4 gB = *(const float4*)&gdT[j][4];
            ge[0] += w * gA.x; ge[1] += w * gA.y; ge[2] += w * gA.z; ge[3] += w * gA.w;
            ge[4] += w * gB.x; ge[5] += w * gB.y; ge[6] += w * gB.z; ge[7] += w * gB.w;
        }
        for (int j = 0; j < 50; ++j) {
            float w = W_tile[dim * 50 + j];
            float4 xA = *(const float4*)&xfT[j][0];
            float4 xB = *(const float4*)&xfT[j][4];
            xe[0] += w * xA.x; xe[1] += w * xA.y; xe[2] += w * xA.z; xe[3] += w * xA.w;
            xe[4] += w * xB.x; xe[5] += w * xB.y; xe[6] += w * xB.z; xe[7] += w * xB.w;
        }
        float4 pA, pB, hA, hB;
        pA.x = leaky_clamp(ge[0] * xe[0]); pA.y = leaky_clamp(ge[1] * xe[1]);
        pA.z = leaky_clamp(ge[2] * xe[2]); pA.w = leaky_clamp(ge[3] * xe[3]);
        pB.x = leaky_clamp(ge[4] * xe[4]); pB.y = leaky_clamp(ge[5] * xe[5]);
        pB.z = leaky_clamp(ge[6] * xe[6]); pB.w = leaky_clamp(ge[7] * xe[7]);
        hA.x = leaky_clamp(ge[0]); hA.y = leaky_clamp(ge[1]);
        hA.z = leaky_clamp(ge[2]); hA.w = leaky_clamp(ge[3]);
        hB.x = leaky_clamp(ge[4]); hB.y = leaky_clamp(ge[5]);
        hB.z = leaky_clamp(ge[6]); hB.w = leaky_clamp(ge[7]);
        *(float4*)&pT[dim][0] = pA; *(float4*)&pT[dim][4] = pB;
        *(float4*)&hT[dim][0] = hA; *(float4*)&hT[dim][4] = hB;
    }
    __syncthreads();

    // lv1 GEMM for all 8 t: W_lv1 streamed ONCE per block
    if (hasD) {
        float acc[kT];
        #pragma unroll
        for (int t = 0; t < kT; ++t) acc[t] = 0.0f;
        #pragma unroll 4
        for (int j = 0; j < kP; ++j) {
            float w = W_lv1[j * kP + dim];
            float4 pA = *(const float4*)&pT[j][0];
            float4 pB = *(const float4*)&pT[j][4];
            acc[0] += w * pA.x; acc[1] += w * pA.y; acc[2] += w * pA.z; acc[3] += w * pA.w;
            acc[4] += w * pB.x; acc[5] += w * pB.y; acc[6] += w * pB.z; acc[7] += w * pB.w;
        }
        *(float4*)&lvT[dim][0] = make_float4(acc[0], acc[1], acc[2], acc[3]);
        *(float4*)&lvT[dim][4] = make_float4(acc[4], acc[5], acc[6], acc[7]);
    }
    __syncthreads();

    // ================= recurrent steps =================
    int par = 0;
    for (int t = 0; t < kT; ++t) {
        // ---- attractor, h in register, 1 barrier/iteration ----
        float h = hasD ? hT[dim][t] : 0.0f;
        if (t == 0) {
            #pragma unroll
            for (int it = 0; it < 5; ++it) h = leaky_clamp(0.8f * h);
        } else {
            for (int it = 0; it < 5; ++it) {
                for (int s = 0; s < t; ++s) {
                    float p = hasD ? s_v[s][dim] * h : 0.0f;
                    #pragma unroll
                    for (int off = 32; off; off >>= 1) p += __shfl_down(p, off, 64);
                    if (lane == 0) s_red[par][s][wid] = p;
                }
                __syncthreads();
                if (hasD) {
                    float mh = 0.0f;
                    float c = 0.5f;
                    for (int s = t - 1; s >= 0; --s) {   // s descending: c = 0.5*0.9999^(t-1-s)
                        float d = 0.0f;
                        #pragma unroll
                        for (int w = 0; w < 8; ++w) d += s_red[par][s][w];
                        mh += c * d * s_u[s][dim];
                        c *= 0.9999f;
                    }
                    h = leaky_clamp(0.8f * h + mh);
                }
                par ^= 1;   // double-buffer: next write goes to other buffer
            }
        }
        if (hasD) s_h[dim] = h;
        __syncthreads();

        // ---- lv2 matvec: thread owns column dim; broadcast LDS reads; 8 chains ----
        float lv2raw = 0.0f;
        if (hasD) {
            float a0=0.f,a1=0.f,a2=0.f,a3=0.f,a4=0.f,a5=0.f,a6=0.f,a7=0.f;
            const float* wp = W_lv2 + dim;
            #pragma unroll 1
            for (int j = 0; j < kP; j += 8) {
                float w0 = wp[(j+0)*kP], w1v = wp[(j+1)*kP];
                float w2v = wp[(j+2)*kP], w3 = wp[(j+3)*kP];
                float w4 = wp[(j+4)*kP], w5 = wp[(j+5)*kP];
                float w6 = wp[(j+6)*kP], w7 = wp[(j+7)*kP];
                a0 += w0 * s_h[j+0]; a1 += w1v * s_h[j+1];
                a2 += w2v * s_h[j+2]; a3 += w3 * s_h[j+3];
                a4 += w4 * s_h[j+4]; a5 += w5 * s_h[j+5];
                a6 += w6 * s_h[j+6]; a7 += w7 * s_h[j+7];
            }
            lv2raw = ((a0 + a1) + (a2 + a3)) + ((a4 + a5) + (a6 + a7)) + blv2;
        }

        // ---- fusion in-register (no extra barrier before) ----
        if (hasD) {
            float lv1raw = lvT[dim][t] + blv1;
            float l1 = -2.0f + 6.0f * tanhf(lv1raw * (1.0f / 6.0f));
            float l2 = -2.0f + 6.0f * tanhf(lv2raw * (1.0f / 6.0f));
            float i1v = expf(-l1), i2v = expf(-l2);
            float pinf = pT[dim][t];
            float p = (pinf * i1v + h * i2v) / (i1v + i2v);
            s_pt[dim] = p;
            s_u[t][dim] = p - h;
            s_v[t][dim] = p + h;
        }
        __syncthreads();

        // ---- generative decode (split partials, short chains) ----
        if (tid < 100) {
            int d = tid % 10, c = tid / 10;
            float acc = 0.0f;
            #pragma unroll
            for (int jj = 0; jj < 10; ++jj) {
                int j = c * 10 + jj;
                acc += s_pt[j] * W_tile0[j * kS + d];
            }
            s_xsp[c][d] = acc;
        }
        __syncthreads();
        if (tid < kS) {
            float acc = 0.0f;
            #pragma unroll
            for (int c = 0; c < 10; ++c) acc += s_xsp[c][tid];
            s_xs[tid] = wx * acc + b_x[tid];
        }
        __syncthreads();
        if (tid < kHid) {
            float acc = b1[tid];
            #pragma unroll
            for (int d = 0; d < kS; ++d)
                acc += s_xs[d] * W1[d * kHid + tid];
            s_hid[tid] = acc > 0.0f ? acc : (expf(acc) - 1.0f);
        }
        __syncthreads();
        if (tid < 360) {
            int o = tid % kObj, c = tid / kObj;
            float acc = 0.0f;
            #pragma unroll
            for (int hh = 0; hh < 25; ++hh) {
                int hI = c * 25 + hh;
                acc += s_hid[hI] * W2[hI * kObj + o];
            }
            s_lp[c][o] = acc;
        }
        __syncthreads();
        if (tid < kObj) {
            float acc = b2[tid];
            #pragma unroll
            for (int c = 0; c < 8; ++c) acc += s_lp[c][tid];
            out[(b * kT + t) * kObj + tid] = acc;
        }
        __syncthreads();
    }
}

extern "C" void kernel_launch(void* const* d_in, const int* in_sizes, int n_in,
                              void* d_out, int out_size, void* d_ws, size_t ws_size,
                              hipStream_t stream) {
    const float* g_seq   = (const float*)d_in[0];
    const int*   x_idx   = (const int*)d_in[1];
    const float* W_comp  = (const float*)d_in[2];
    const float* W_repeat= (const float*)d_in[3];
    const float* W_tile  = (const float*)d_in[4];
    const float* W_tile0 = (const float*)d_in[5];
    const float* w_x     = (const float*)d_in[6];
    const float* b_x     = (const float*)d_in[7];
    const float* W1      = (const float*)d_in[8];
    const float* b1      = (const float*)d_in[9];
    const float* W2      = (const float*)d_in[10];
    const float* b2      = (const float*)d_in[11];
    const float* W_lv1   = (const float*)d_in[12];
    const float* b_lv1   = (const float*)d_in[13];
    const float* W_lv2   = (const float*)d_in[14];
    const float* b_lv2   = (const float*)d_in[15];
    float* out = (float*)d_out;

    const int Bn = in_sizes[0] / (kT * kG);
    tem_kernel<<<dim3(Bn), dim3(512), 0, stream>>>(
        g_seq, x_idx, W_comp, W_repeat, W_tile, W_tile0, w_x, b_x,
        W1, b1, W2, b2, W_lv1, b_lv1, W_lv2, b_lv2, out);
}

// Round 13
// 249.283 us; speedup vs baseline: 3.4015x; 1.0251x over previous
//
// R13: R12 + float4 lv2 matvec. Per-step serial load rounds 50 -> ~12.5:
// 4 groups x 128 thr; group g covers j in [100g,100g+100); thread r<100 owns
// dims 4r..4r+3 (coalesced float4 along i, ORIGINAL layout — R10 taught us
// never to vectorize along the per-thread axis). Partials combined in LDS.
// Everything else verbatim from R12 (passed, 200us counter-dur).
#include <hip/hip_runtime.h>

#define kT 8
#define kG 120
#define kP 400
#define kObj 45
#define kS 10
#define kHid 200

__device__ __constant__ int c_gmap[40] = {
    0,1,2,3,4,5,6,7,8,9,
    30,31,32,33,34,35,36,37,38,39,
    60,61,62,63,64,65,66,67,
    84,85,86,87,88,89,
    102,103,104,105,106,107};

__device__ __constant__ float c_freq[5] = {0.01f, 0.7f, 0.91f, 0.97f, 0.99f};

__device__ __forceinline__ float leaky_clamp(float x) {
    x = fminf(fmaxf(x, -1.0f), 1.0f);
    return x > 0.0f ? x : 0.01f * x;
}

__global__ __launch_bounds__(512) void tem_kernel(
    const float* __restrict__ g_seq, const int* __restrict__ x_idx,
    const float* __restrict__ W_comp, const float* __restrict__ W_repeat,
    const float* __restrict__ W_tile, const float* __restrict__ W_tile0,
    const float* __restrict__ w_x, const float* __restrict__ b_x,
    const float* __restrict__ W1, const float* __restrict__ b1,
    const float* __restrict__ W2, const float* __restrict__ b2,
    const float* __restrict__ W_lv1, const float* __restrict__ b_lv1,
    const float* __restrict__ W_lv2, const float* __restrict__ b_lv2,
    float* __restrict__ out)
{
    const int b   = blockIdx.x;
    const int tid = threadIdx.x;
    const int dim = tid;
    const bool hasD = (tid < kP);
    const int wid  = tid >> 6;
    const int lane = tid & 63;
    const int g   = tid >> 7;            // 0..3 matvec group
    const int r   = tid & 127;           // 0..127
    const bool mact = (r < 100);
    const int j0  = g * 100;             // j-quarter

    __shared__ __align__(16) float pT[kP][kT];    // p_inf, t-minor
    __shared__ __align__(16) float hT[kP][kT];    // h_init = lc(g_exp)
    __shared__ __align__(16) float lvT[kP][kT];   // lv1raw (pre-bias)
    __shared__ __align__(16) float xfT[50][kT];   // x_filt, t-minor
    __shared__ __align__(16) float gdT[40][kT];   // g_down, t-minor
    __shared__ float s_h[kP];                     // p_ret of current step
    __shared__ float s_pt[kP];
    __shared__ float s_u[kT][kP];
    __shared__ float s_v[kT][kP];
    __shared__ __align__(16) float s_part[4][kP]; // lv2 partials per group
    __shared__ float s_red[2][kT][8];             // [parity][s][wave]
    __shared__ int   s_idx[kT];
    __shared__ float s_xsp[kS][kS];               // [chunk][d]
    __shared__ float s_xs[kS];
    __shared__ float s_hid[kHid];
    __shared__ float s_lp[8][kObj];

    const float blv1 = hasD ? b_lv1[dim] : 0.0f;
    const float blv2 = hasD ? b_lv2[dim] : 0.0f;
    const float wx   = w_x[0];

    // ================= prologue =================
    if (tid < kT) s_idx[tid] = x_idx[b * kT + tid];
    __syncthreads();

    if (tid < 40) {
        int gi = c_gmap[tid];
        #pragma unroll
        for (int t = 0; t < kT; ++t)
            gdT[tid][t] = g_seq[(b * kT + t) * kG + gi];
    } else if (tid >= 64 && tid < 114) {
        int rr = tid - 64, d = rr % 10;
        float f = c_freq[rr / 10];
        float xf = 0.0f;
        #pragma unroll
        for (int t = 0; t < kT; ++t) {
            float xc = W_comp[s_idx[t] * kS + d];
            xf = (1.0f - f) * xf + f * xc;
            xfT[rr][t] = xf;
        }
    }
    __syncthreads();

    // projections for all 8 t: g_exp, x_exp -> p_inf, h_init
    if (hasD) {
        float ge[kT], xe[kT];
        #pragma unroll
        for (int t = 0; t < kT; ++t) { ge[t] = 0.0f; xe[t] = 0.0f; }
        for (int j = 0; j < 40; ++j) {
            float w = W_repeat[dim * 40 + j];
            float4 gA = *(const float4*)&gdT[j][0];
            float4 gB = *(const float4*)&gdT[j][4];
            ge[0] += w * gA.x; ge[1] += w * gA.y; ge[2] += w * gA.z; ge[3] += w * gA.w;
            ge[4] += w * gB.x; ge[5] += w * gB.y; ge[6] += w * gB.z; ge[7] += w * gB.w;
        }
        for (int j = 0; j < 50; ++j) {
            float w = W_tile[dim * 50 + j];
            float4 xA = *(const float4*)&xfT[j][0];
            float4 xB = *(const float4*)&xfT[j][4];
            xe[0] += w * xA.x; xe[1] += w * xA.y; xe[2] += w * xA.z; xe[3] += w * xA.w;
            xe[4] += w * xB.x; xe[5] += w * xB.y; xe[6] += w * xB.z; xe[7] += w * xB.w;
        }
        float4 pA, pB, hA, hB;
        pA.x = leaky_clamp(ge[0] * xe[0]); pA.y = leaky_clamp(ge[1] * xe[1]);
        pA.z = leaky_clamp(ge[2] * xe[2]); pA.w = leaky_clamp(ge[3] * xe[3]);
        pB.x = leaky_clamp(ge[4] * xe[4]); pB.y = leaky_clamp(ge[5] * xe[5]);
        pB.z = leaky_clamp(ge[6] * xe[6]); pB.w = leaky_clamp(ge[7] * xe[7]);
        hA.x = leaky_clamp(ge[0]); hA.y = leaky_clamp(ge[1]);
        hA.z = leaky_clamp(ge[2]); hA.w = leaky_clamp(ge[3]);
        hB.x = leaky_clamp(ge[4]); hB.y = leaky_clamp(ge[5]);
        hB.z = leaky_clamp(ge[6]); hB.w = leaky_clamp(ge[7]);
        *(float4*)&pT[dim][0] = pA; *(float4*)&pT[dim][4] = pB;
        *(float4*)&hT[dim][0] = hA; *(float4*)&hT[dim][4] = hB;
    }
    __syncthreads();

    // lv1 GEMM for all 8 t: W_lv1 streamed ONCE per block
    if (hasD) {
        float acc[kT];
        #pragma unroll
        for (int t = 0; t < kT; ++t) acc[t] = 0.0f;
        #pragma unroll 4
        for (int j = 0; j < kP; ++j) {
            float w = W_lv1[j * kP + dim];
            float4 pA = *(const float4*)&pT[j][0];
            float4 pB = *(const float4*)&pT[j][4];
            acc[0] += w * pA.x; acc[1] += w * pA.y; acc[2] += w * pA.z; acc[3] += w * pA.w;
            acc[4] += w * pB.x; acc[5] += w * pB.y; acc[6] += w * pB.z; acc[7] += w * pB.w;
        }
        *(float4*)&lvT[dim][0] = make_float4(acc[0], acc[1], acc[2], acc[3]);
        *(float4*)&lvT[dim][4] = make_float4(acc[4], acc[5], acc[6], acc[7]);
    }
    __syncthreads();

    // ================= recurrent steps =================
    int par = 0;
    for (int t = 0; t < kT; ++t) {
        // ---- attractor, h in register, 1 barrier/iteration ----
        float h = hasD ? hT[dim][t] : 0.0f;
        if (t == 0) {
            #pragma unroll
            for (int it = 0; it < 5; ++it) h = leaky_clamp(0.8f * h);
        } else {
            for (int it = 0; it < 5; ++it) {
                for (int s = 0; s < t; ++s) {
                    float p = hasD ? s_v[s][dim] * h : 0.0f;
                    #pragma unroll
                    for (int off = 32; off; off >>= 1) p += __shfl_down(p, off, 64);
                    if (lane == 0) s_red[par][s][wid] = p;
                }
                __syncthreads();
                if (hasD) {
                    float mh = 0.0f;
                    float c = 0.5f;
                    for (int s = t - 1; s >= 0; --s) {
                        float d = 0.0f;
                        #pragma unroll
                        for (int w = 0; w < 8; ++w) d += s_red[par][s][w];
                        mh += c * d * s_u[s][dim];
                        c *= 0.9999f;
                    }
                    h = leaky_clamp(0.8f * h + mh);
                }
                par ^= 1;
            }
        }
        if (hasD) s_h[dim] = h;
        __syncthreads();

        // ---- lv2 matvec: 4 groups x j-quarter, float4 along i, partials in LDS ----
        if (mact) {
            float4 a0{0,0,0,0}, a1{0,0,0,0}, a2{0,0,0,0}, a3{0,0,0,0};
            #pragma unroll 2
            for (int jj = 0; jj < 100; jj += 4) {
                int j = j0 + jj;
                float4 w0 = ((const float4*)(W_lv2 + (j+0) * kP))[r];
                float4 w1v = ((const float4*)(W_lv2 + (j+1) * kP))[r];
                float4 w2v = ((const float4*)(W_lv2 + (j+2) * kP))[r];
                float4 w3 = ((const float4*)(W_lv2 + (j+3) * kP))[r];
                float v0 = s_h[j+0], v1 = s_h[j+1], v2 = s_h[j+2], v3 = s_h[j+3];
                a0.x += w0.x * v0; a0.y += w0.y * v0; a0.z += w0.z * v0; a0.w += w0.w * v0;
                a1.x += w1v.x * v1; a1.y += w1v.y * v1; a1.z += w1v.z * v1; a1.w += w1v.w * v1;
                a2.x += w2v.x * v2; a2.y += w2v.y * v2; a2.z += w2v.z * v2; a2.w += w2v.w * v2;
                a3.x += w3.x * v3; a3.y += w3.y * v3; a3.z += w3.z * v3; a3.w += w3.w * v3;
            }
            float4 tot;
            tot.x = (a0.x + a1.x) + (a2.x + a3.x);
            tot.y = (a0.y + a1.y) + (a2.y + a3.y);
            tot.z = (a0.z + a1.z) + (a2.z + a3.z);
            tot.w = (a0.w + a1.w) + (a2.w + a3.w);
            ((float4*)&s_part[g][0])[r] = tot;
        }
        __syncthreads();

        // ---- fusion (thread owns dim) ----
        if (hasD) {
            float lv2raw = (s_part[0][dim] + s_part[1][dim])
                         + (s_part[2][dim] + s_part[3][dim]) + blv2;
            float lv1raw = lvT[dim][t] + blv1;
            float l1 = -2.0f + 6.0f * tanhf(lv1raw * (1.0f / 6.0f));
            float l2 = -2.0f + 6.0f * tanhf(lv2raw * (1.0f / 6.0f));
            float i1v = expf(-l1), i2v = expf(-l2);
            float pinf = pT[dim][t];
            float p = (pinf * i1v + h * i2v) / (i1v + i2v);
            s_pt[dim] = p;
            s_u[t][dim] = p - h;
            s_v[t][dim] = p + h;
        }
        __syncthreads();

        // ---- generative decode ----
        if (tid < 100) {
            int d = tid % 10, c = tid / 10;
            float acc = 0.0f;
            #pragma unroll
            for (int jj = 0; jj < 10; ++jj) {
                int j = c * 10 + jj;
                acc += s_pt[j] * W_tile0[j * kS + d];
            }
            s_xsp[c][d] = acc;
        }
        __syncthreads();
        if (tid < kS) {
            float acc = 0.0f;
            #pragma unroll
            for (int c = 0; c < 10; ++c) acc += s_xsp[c][tid];
            s_xs[tid] = wx * acc + b_x[tid];
        }
        __syncthreads();
        if (tid < kHid) {
            float acc = b1[tid];
            #pragma unroll
            for (int d = 0; d < kS; ++d)
                acc += s_xs[d] * W1[d * kHid + tid];
            s_hid[tid] = acc > 0.0f ? acc : (expf(acc) - 1.0f);
        }
        __syncthreads();
        if (tid < 360) {
            int o = tid % kObj, c = tid / kObj;
            float acc = 0.0f;
            #pragma unroll
            for (int hh = 0; hh < 25; ++hh) {
                int hI = c * 25 + hh;
                acc += s_hid[hI] * W2[hI * kObj + o];
            }
            s_lp[c][o] = acc;
        }
        __syncthreads();
        if (tid < kObj) {
            float acc = b2[tid];
            #pragma unroll
            for (int c = 0; c < 8; ++c) acc += s_lp[c][tid];
            out[(b * kT + t) * kObj + tid] = acc;
        }
        __syncthreads();
    }
}

extern "C" void kernel_launch(void* const* d_in, const int* in_sizes, int n_in,
                              void* d_out, int out_size, void* d_ws, size_t ws_size,
                              hipStream_t stream) {
    const float* g_seq   = (const float*)d_in[0];
    const int*   x_idx   = (const int*)d_in[1];
    const float* W_comp  = (const float*)d_in[2];
    const float* W_repeat= (const float*)d_in[3];
    const float* W_tile  = (const float*)d_in[4];
    const float* W_tile0 = (const float*)d_in[5];
    const float* w_x     = (const float*)d_in[6];
    const float* b_x     = (const float*)d_in[7];
    const float* W1      = (const float*)d_in[8];
    const float* b1      = (const float*)d_in[9];
    const float* W2      = (const float*)d_in[10];
    const float* b2      = (const float*)d_in[11];
    const float* W_lv1   = (const float*)d_in[12];
    const float* b_lv1   = (const float*)d_in[13];
    const float* W_lv2   = (const float*)d_in[14];
    const float* b_lv2   = (const float*)d_in[15];
    float* out = (float*)d_out;

    const int Bn = in_sizes[0] / (kT * kG);
    tem_kernel<<<dim3(Bn), dim3(512), 0, stream>>>(
        g_seq, x_idx, W_comp, W_repeat, W_tile, W_tile0, w_x, b_x,
        W1, b1, W2, b2, W_lv1, b_lv1, W_lv2, b_lv2, out);
}